// Round 3
// baseline (179.693 us; speedup 1.0000x reference)
//
#include <hip/hip_runtime.h>
#include <math.h>

#define M_ 48
#define L_ 48
#define N_ 256
#define THREADS 256
#define NWAVE 4
#define PPT 5                  // pairs per thread: one row-chunk of 5 consecutive k

// R12: MEASUREMENT ROUND. Kernel body is R11 unchanged (f32 LDS table, f64
// math — measured 83.9 us, passed, absmax 0). kernel_launch now launches the
// kernel 5x back-to-back: K = (dur_us - 83.9)/4 resolves the kernel's true
// duration, which is currently unobservable (top-5 rocprof rows are all
// 39.5 us harness fills; bottom-up model says ~12 us, prior session claimed
// ~30 us, harness-floor world says ~4 us — three different strategies).
// Kernel is deterministic + idempotent => repeated launch is bit-identical.
// Post-mortem R11: LDS table width halving was NEUTRAL (+1.1 us ~ noise) =>
// ckpt/stash LDS bandwidth is NOT on the critical path; theory rejected.
// Prior dead ends (measured): R8 2x3 tiles, R9 spread prefetch, R10 ckpt-pass
// stash capture (VGPR blowout -> scratch spill, FETCH x8).
struct ChunkTab { short cm[256]; short ck0[256]; };
constexpr ChunkTab make_tab() {
    ChunkTab t{};
    int bsz[16] = {};
    for (int m = 0; m < 48; ++m)
        for (int j = 0; 5 * j < 48 - m; ++j) bsz[(m + 5 * j) & 15]++;
    int slot = 0;
    for (int r = 0; r < 48; ++r)
        for (int b = 0; b < 16; ++b)
            if (bsz[b] > r) {
                int cnt = 0;
                for (int m = 0; m < 48; ++m)
                    for (int j = 0; 5 * j < 48 - m; ++j)
                        if (((m + 5 * j) & 15) == b) {
                            if (cnt == r) { t.cm[slot] = (short)m; t.ck0[slot] = (short)(m + 5 * j); }
                            ++cnt;
                        }
                ++slot;
            }
    for (; slot < 256; ++slot) { t.cm[slot] = 0; t.ck0[slot] = 127; }  // dummy: weights 0
    return t;
}
__device__ constexpr ChunkTab g_tab = make_tab();

// f64 DPP wave-sum; lane 63 ends with the 64-lane total (VALU-latency stages,
// not ds_bpermute: R7's key win).
template<int CTRL, int RMASK>
__device__ __forceinline__ double dpp_add(double v) {
    int lo = __builtin_amdgcn_update_dpp(0, __double2loint(v), CTRL, RMASK, 0xf, true);
    int hi = __builtin_amdgcn_update_dpp(0, __double2hiint(v), CTRL, RMASK, 0xf, true);
    return v + __hiloint2double(hi, lo);
}
__device__ __forceinline__ double wave_sum63(double v) {
    v = dpp_add<0x111, 0xf>(v);   // row_shr:1
    v = dpp_add<0x112, 0xf>(v);   // row_shr:2
    v = dpp_add<0x114, 0xf>(v);   // row_shr:4
    v = dpp_add<0x118, 0xf>(v);   // row_shr:8
    v = dpp_add<0x142, 0xa>(v);   // row_bcast15
    v = dpp_add<0x143, 0xc>(v);   // row_bcast31 -> lane63 = total
    return v;
}

__launch_bounds__(THREADS, 1)
__global__ void mps_sample_kernel(const float* __restrict__ inp,
                                  const float* __restrict__ theta,
                                  const float* __restrict__ coef,
                                  const float* __restrict__ rand_u,
                                  float* __restrict__ out)
{
    const int n   = blockIdx.x;
    const int tid = threadIdx.x;

    __shared__ float  s_pxy[L_][M_][2];        // (px,py) f32 interleaved, b64-readable
    __shared__ double s_part[2][4][NWAVE];     // [parity][value][wave]
    __shared__ float  s_u[L_];

    const double PI_2 = 1.5707963267948966;

    // ---- trig init: pxy[l][m] = coef[m] * (cos, sin)(theta + inp*(m+1)*pi/2) ----
    #pragma unroll
    for (int i = 0; i < 9; ++i) {
        int j = tid + THREADS * i;
        int l = j / M_, m = j - l * M_;
        double a  = (double)inp[n * L_ + l] * ((double)(m + 1) * PI_2);
        double th = (double)theta[l * M_ + m];
        double sv, cv; sincos(th + a, &sv, &cv);
        double cf = (double)coef[m];
        s_pxy[l][m][0] = (float)(cf * cv);
        s_pxy[l][m][1] = (float)(cf * sv);
    }
    if (tid < L_) s_u[tid] = rand_u[tid * N_ + n];

    // ---- row-chunk pair assignment: 5 pairs (cm, k0..k0+4) per thread ----
    const int cm = g_tab.cm[tid];
    const int k0 = g_tab.ck0[tid];
    int pk[PPT]; double wgt[PPT];
    #pragma unroll
    for (int i = 0; i < PPT; ++i) {
        int k = k0 + i;
        wgt[i] = (k > 47) ? 0.0 : ((k == cm) ? 1.0 : 2.0);
        pk[i]  = (k > 47) ? 47 : k;
    }
    __syncthreads();

    // ---- register checkpoints: ckpt[s] = w * prod_{l'>=8(s+1)} T_l' ----
    double ckpt[5][PPT];
    {
        double C[PPT];
        #pragma unroll
        for (int i = 0; i < PPT; ++i) C[i] = wgt[i];
        #pragma unroll
        for (int s = 4; s >= 0; --s) {
            #pragma unroll
            for (int lp = 7; lp >= 0; --lp) {
                int l = 8 * (s + 1) + lp;              // 47 .. 8
                float2 vm = *(const float2*)&s_pxy[l][cm][0];   // shared per thread
                #pragma unroll
                for (int i = 0; i < PPT; ++i) {
                    float2 vk = *(const float2*)&s_pxy[l][pk[i]][0];
                    C[i] *= (double)fmaf(vm.x, vk.x, vm.y * vk.y);
                }
            }
            #pragma unroll
            for (int i = 0; i < PPT; ++i) ckpt[s][i] = C[i];
        }
    }

    double G[PPT];
    #pragma unroll
    for (int i = 0; i < PPT; ++i) G[i] = 1.0;

    double denom = 0.0, initd = 1.0;
    float  myBit = 0.0f;

    #pragma unroll
    for (int seg = 0; seg < 6; ++seg) {
        // ---- segment stash: X[j][i], Y[j][i] (1 vm + 5 vk b64 loads per site) ----
        double X[8][PPT], Y[8][PPT];
        #pragma unroll
        for (int j = 0; j < 8; ++j) {
            int l2 = 8 * seg + j;
            float2 vm = *(const float2*)&s_pxy[l2][cm][0];
            #pragma unroll
            for (int i = 0; i < PPT; ++i) {
                float2 vk = *(const float2*)&s_pxy[l2][pk[i]][0];
                X[j][i] = (double)(vm.x * vk.x);
                Y[j][i] = (double)(vm.y * vk.y);
            }
        }
        // ---- register expansion from stash: R[j] = w * S_{8seg+j+1} ----
        double R[8][PPT];
        #pragma unroll
        for (int i = 0; i < PPT; ++i)
            R[7][i] = (seg == 5) ? wgt[i] : ckpt[seg == 5 ? 0 : seg][i];
        #pragma unroll
        for (int j = 6; j >= 0; --j)
            #pragma unroll
            for (int i = 0; i < PPT; ++i)
                R[j][i] = R[j + 1][i] * (X[j + 1][i] + Y[j + 1][i]);

        // ---- 4 iterations x 2 speculative steps, DPP-reduced ----
        #pragma unroll
        for (int half = 0; half < 4; ++half) {
            const int ls  = 2 * half;
            const int l   = 8 * seg + ls;
            const int par = half & 1;
            double n1L = 0.0, h0 = 0.0, h1 = 0.0, nT = 0.0;
            #pragma unroll
            for (int i = 0; i < PPT; ++i) {
                double t0 = G[i] * R[ls][i];
                double t1 = G[i] * R[ls + 1][i];
                n1L = fma(t0, Y[ls][i], n1L);
                if (seg == 0 && half == 0) nT = fma(t0, X[0][i], nT); // denom seed
                h0 = fma(t1 * X[ls][i], Y[ls + 1][i], h0);   // hypothesis bit_l = 0
                h1 = fma(t1 * Y[ls][i], Y[ls + 1][i], h1);   // hypothesis bit_l = 1
            }
            n1L = wave_sum63(n1L);
            h0  = wave_sum63(h0);
            h1  = wave_sum63(h1);
            if (seg == 0 && half == 0) nT = wave_sum63(nT);
            if ((tid & 63) == 63) {                 // lane 63 holds wave totals
                const int wv = tid >> 6;
                s_part[par][0][wv] = n1L; s_part[par][1][wv] = h0;
                s_part[par][2][wv] = h1;
                if (seg == 0 && half == 0) s_part[par][3][wv] = nT;
            }
            __syncthreads();
            double2 a0 = *(const double2*)&s_part[par][0][0];
            double2 b0 = *(const double2*)&s_part[par][0][2];
            double2 a1 = *(const double2*)&s_part[par][1][0];
            double2 b1 = *(const double2*)&s_part[par][1][2];
            double2 a2 = *(const double2*)&s_part[par][2][0];
            double2 b2 = *(const double2*)&s_part[par][2][2];
            double sn1 = (a0.x + a0.y) + (b0.x + b0.y);
            double sh0 = (a1.x + a1.y) + (b1.x + b1.y);
            double sh1 = (a2.x + a2.y) + (b2.x + b2.y);
            if (seg == 0 && half == 0) {
                double2 a3 = *(const double2*)&s_part[par][3][0];
                double2 b3 = *(const double2*)&s_part[par][3][2];
                double snT = (a3.x + a3.y) + (b3.x + b3.y);
                denom = fabs(snT + sn1);
                initd = denom;
            }
            // two bit decisions, division-free (denom = <psi|psi> > 0)
            double v1 = fabs(sn1);
            int bitA   = ((double)s_u[l] * denom < v1) ? 1 : 0;
            denom      = bitA ? v1 : fabs(denom - sn1);
            double n1b = bitA ? sh1 : sh0;
            double v2  = fabs(n1b);
            int bitB   = ((double)s_u[l + 1] * denom < v2) ? 1 : 0;
            denom      = bitB ? v2 : fabs(denom - n1b);
            // fused two-step prefix update from stash
            #pragma unroll
            for (int i = 0; i < PPT; ++i) {
                double c0 = bitA ? Y[ls][i]     : X[ls][i];
                double c1 = bitB ? Y[ls + 1][i] : X[ls + 1][i];
                G[i] *= c0 * c1;
            }
            if (tid == l)     myBit = (float)bitA;
            if (tid == l + 1) myBit = (float)bitB;
        }
    }

    if (tid < L_)  out[n * L_ + tid] = myBit;                 // bits, one burst
    if (tid == 0)  out[N_ * L_ + n] = (float)(denom / initd); // P_m carried free
}

extern "C" void kernel_launch(void* const* d_in, const int* in_sizes, int n_in,
                              void* d_out, int out_size, void* d_ws, size_t ws_size,
                              hipStream_t stream) {
    const float* inp    = (const float*)d_in[0];   // (N,L)
    const float* theta  = (const float*)d_in[1];   // (L,M)
    const float* coef   = (const float*)d_in[2];   // (M,)
    const float* rand_u = (const float*)d_in[3];   // (L,N)
    float* out = (float*)d_out;                    // N*L bits then N probs
    // R12 measurement: 5 idempotent launches. K = (dur_us - 83.9)/4.
    for (int rep = 0; rep < 5; ++rep)
        mps_sample_kernel<<<N_, THREADS, 0, stream>>>(inp, theta, coef, rand_u, out);
}

// Round 4
// 142.408 us; speedup vs baseline: 1.2618x; 1.2618x over previous
//
#include <hip/hip_runtime.h>
#include <math.h>

#define M_ 48
#define L_ 48
#define N_ 256
#define THREADS 256
#define NWAVE 4
#define PPT 5                  // pairs per thread: one row-chunk of 5 consecutive k
#define REP 4                  // R13: internal replay so the kernel tops the counter table

// R13: COUNTER-VISIBILITY ROUND. Body is R11 unchanged; whole body replayed
// REP=4x inside one dispatch (~96 us > 39.5 us harness fills) so rocprof's
// top-5 finally shows OUR kernel's VALUBusy / VGPR / bank-conflict / occupancy.
// R12 measured K ~= 24 us/launch (5-launch probe: (179.7-83.9)/4), ~2x the
// bottom-up issue model (~9 us) -> need VALUBusy to discriminate
// latency-bound (<45%) vs issue/clock-bound (>65%) before editing further.
// Post-mortems: R11 f32-LDS-table NEUTRAL (LDS BW not critical path).
// Dead ends (measured): R8 2x3 tiles, R9 spread prefetch, R10 stash capture.
struct ChunkTab { short cm[256]; short ck0[256]; };
constexpr ChunkTab make_tab() {
    ChunkTab t{};
    int bsz[16] = {};
    for (int m = 0; m < 48; ++m)
        for (int j = 0; 5 * j < 48 - m; ++j) bsz[(m + 5 * j) & 15]++;
    int slot = 0;
    for (int r = 0; r < 48; ++r)
        for (int b = 0; b < 16; ++b)
            if (bsz[b] > r) {
                int cnt = 0;
                for (int m = 0; m < 48; ++m)
                    for (int j = 0; 5 * j < 48 - m; ++j)
                        if (((m + 5 * j) & 15) == b) {
                            if (cnt == r) { t.cm[slot] = (short)m; t.ck0[slot] = (short)(m + 5 * j); }
                            ++cnt;
                        }
                ++slot;
            }
    for (; slot < 256; ++slot) { t.cm[slot] = 0; t.ck0[slot] = 127; }  // dummy: weights 0
    return t;
}
__device__ constexpr ChunkTab g_tab = make_tab();

// f64 DPP wave-sum; lane 63 ends with the 64-lane total (VALU-latency stages,
// not ds_bpermute: R7's key win).
template<int CTRL, int RMASK>
__device__ __forceinline__ double dpp_add(double v) {
    int lo = __builtin_amdgcn_update_dpp(0, __double2loint(v), CTRL, RMASK, 0xf, true);
    int hi = __builtin_amdgcn_update_dpp(0, __double2hiint(v), CTRL, RMASK, 0xf, true);
    return v + __hiloint2double(hi, lo);
}
__device__ __forceinline__ double wave_sum63(double v) {
    v = dpp_add<0x111, 0xf>(v);   // row_shr:1
    v = dpp_add<0x112, 0xf>(v);   // row_shr:2
    v = dpp_add<0x114, 0xf>(v);   // row_shr:4
    v = dpp_add<0x118, 0xf>(v);   // row_shr:8
    v = dpp_add<0x142, 0xa>(v);   // row_bcast15
    v = dpp_add<0x143, 0xc>(v);   // row_bcast31 -> lane63 = total
    return v;
}

__launch_bounds__(THREADS, 1)
__global__ void mps_sample_kernel(const float* __restrict__ inp,
                                  const float* __restrict__ theta,
                                  const float* __restrict__ coef,
                                  const float* __restrict__ rand_u,
                                  float* __restrict__ out)
{
    const int n   = blockIdx.x;
    const int tid = threadIdx.x;

    __shared__ float  s_pxy[L_][M_][2];        // (px,py) f32 interleaved, b64-readable
    __shared__ double s_part[2][4][NWAVE];     // [parity][value][wave]
    __shared__ float  s_u[L_];

    const double PI_2 = 1.5707963267948966;

    // ---- row-chunk pair assignment: 5 pairs (cm, k0..k0+4) per thread ----
    const int cm = g_tab.cm[tid];
    const int k0 = g_tab.ck0[tid];
    int pk[PPT]; double wgt[PPT];
    #pragma unroll
    for (int i = 0; i < PPT; ++i) {
        int k = k0 + i;
        wgt[i] = (k > 47) ? 0.0 : ((k == cm) ? 1.0 : 2.0);
        pk[i]  = (k > 47) ? 47 : k;
    }

    double denom = 0.0, initd = 1.0;
    float  myBit = 0.0f;

    for (int rep = 0; rep < REP; ++rep) {
        __syncthreads();   // rep-boundary: prior rep's s_u/s_part reads done before re-init

        // ---- trig init: pxy[l][m] = coef[m] * (cos, sin)(theta + inp*(m+1)*pi/2) ----
        #pragma unroll
        for (int i = 0; i < 9; ++i) {
            int j = tid + THREADS * i;
            int l = j / M_, m = j - l * M_;
            double a  = (double)inp[n * L_ + l] * ((double)(m + 1) * PI_2);
            double th = (double)theta[l * M_ + m];
            double sv, cv; sincos(th + a, &sv, &cv);
            double cf = (double)coef[m];
            s_pxy[l][m][0] = (float)(cf * cv);
            s_pxy[l][m][1] = (float)(cf * sv);
        }
        if (tid < L_) s_u[tid] = rand_u[tid * N_ + n];
        __syncthreads();

        // ---- register checkpoints: ckpt[s] = w * prod_{l'>=8(s+1)} T_l' ----
        double ckpt[5][PPT];
        {
            double C[PPT];
            #pragma unroll
            for (int i = 0; i < PPT; ++i) C[i] = wgt[i];
            #pragma unroll
            for (int s = 4; s >= 0; --s) {
                #pragma unroll
                for (int lp = 7; lp >= 0; --lp) {
                    int l = 8 * (s + 1) + lp;              // 47 .. 8
                    float2 vm = *(const float2*)&s_pxy[l][cm][0];   // shared per thread
                    #pragma unroll
                    for (int i = 0; i < PPT; ++i) {
                        float2 vk = *(const float2*)&s_pxy[l][pk[i]][0];
                        C[i] *= (double)fmaf(vm.x, vk.x, vm.y * vk.y);
                    }
                }
                #pragma unroll
                for (int i = 0; i < PPT; ++i) ckpt[s][i] = C[i];
            }
        }

        double G[PPT];
        #pragma unroll
        for (int i = 0; i < PPT; ++i) G[i] = 1.0;

        denom = 0.0; initd = 1.0;

        #pragma unroll
        for (int seg = 0; seg < 6; ++seg) {
            // ---- segment stash: X[j][i], Y[j][i] (1 vm + 5 vk b64 loads per site) ----
            double X[8][PPT], Y[8][PPT];
            #pragma unroll
            for (int j = 0; j < 8; ++j) {
                int l2 = 8 * seg + j;
                float2 vm = *(const float2*)&s_pxy[l2][cm][0];
                #pragma unroll
                for (int i = 0; i < PPT; ++i) {
                    float2 vk = *(const float2*)&s_pxy[l2][pk[i]][0];
                    X[j][i] = (double)(vm.x * vk.x);
                    Y[j][i] = (double)(vm.y * vk.y);
                }
            }
            // ---- register expansion from stash: R[j] = w * S_{8seg+j+1} ----
            double R[8][PPT];
            #pragma unroll
            for (int i = 0; i < PPT; ++i)
                R[7][i] = (seg == 5) ? wgt[i] : ckpt[seg == 5 ? 0 : seg][i];
            #pragma unroll
            for (int j = 6; j >= 0; --j)
                #pragma unroll
                for (int i = 0; i < PPT; ++i)
                    R[j][i] = R[j + 1][i] * (X[j + 1][i] + Y[j + 1][i]);

            // ---- 4 iterations x 2 speculative steps, DPP-reduced ----
            #pragma unroll
            for (int half = 0; half < 4; ++half) {
                const int ls  = 2 * half;
                const int l   = 8 * seg + ls;
                const int par = half & 1;
                double n1L = 0.0, h0 = 0.0, h1 = 0.0, nT = 0.0;
                #pragma unroll
                for (int i = 0; i < PPT; ++i) {
                    double t0 = G[i] * R[ls][i];
                    double t1 = G[i] * R[ls + 1][i];
                    n1L = fma(t0, Y[ls][i], n1L);
                    if (seg == 0 && half == 0) nT = fma(t0, X[0][i], nT); // denom seed
                    h0 = fma(t1 * X[ls][i], Y[ls + 1][i], h0);   // hypothesis bit_l = 0
                    h1 = fma(t1 * Y[ls][i], Y[ls + 1][i], h1);   // hypothesis bit_l = 1
                }
                n1L = wave_sum63(n1L);
                h0  = wave_sum63(h0);
                h1  = wave_sum63(h1);
                if (seg == 0 && half == 0) nT = wave_sum63(nT);
                if ((tid & 63) == 63) {                 // lane 63 holds wave totals
                    const int wv = tid >> 6;
                    s_part[par][0][wv] = n1L; s_part[par][1][wv] = h0;
                    s_part[par][2][wv] = h1;
                    if (seg == 0 && half == 0) s_part[par][3][wv] = nT;
                }
                __syncthreads();
                double2 a0 = *(const double2*)&s_part[par][0][0];
                double2 b0 = *(const double2*)&s_part[par][0][2];
                double2 a1 = *(const double2*)&s_part[par][1][0];
                double2 b1 = *(const double2*)&s_part[par][1][2];
                double2 a2 = *(const double2*)&s_part[par][2][0];
                double2 b2 = *(const double2*)&s_part[par][2][2];
                double sn1 = (a0.x + a0.y) + (b0.x + b0.y);
                double sh0 = (a1.x + a1.y) + (b1.x + b1.y);
                double sh1 = (a2.x + a2.y) + (b2.x + b2.y);
                if (seg == 0 && half == 0) {
                    double2 a3 = *(const double2*)&s_part[par][3][0];
                    double2 b3 = *(const double2*)&s_part[par][3][2];
                    double snT = (a3.x + a3.y) + (b3.x + b3.y);
                    denom = fabs(snT + sn1);
                    initd = denom;
                }
                // two bit decisions, division-free (denom = <psi|psi> > 0)
                double v1 = fabs(sn1);
                int bitA   = ((double)s_u[l] * denom < v1) ? 1 : 0;
                denom      = bitA ? v1 : fabs(denom - sn1);
                double n1b = bitA ? sh1 : sh0;
                double v2  = fabs(n1b);
                int bitB   = ((double)s_u[l + 1] * denom < v2) ? 1 : 0;
                denom      = bitB ? v2 : fabs(denom - n1b);
                // fused two-step prefix update from stash
                #pragma unroll
                for (int i = 0; i < PPT; ++i) {
                    double c0 = bitA ? Y[ls][i]     : X[ls][i];
                    double c1 = bitB ? Y[ls + 1][i] : X[ls + 1][i];
                    G[i] *= c0 * c1;
                }
                if (tid == l)     myBit = (float)bitA;
                if (tid == l + 1) myBit = (float)bitB;
            }
        }
    }

    if (tid < L_)  out[n * L_ + tid] = myBit;                 // bits, one burst
    if (tid == 0)  out[N_ * L_ + n] = (float)(denom / initd); // P_m carried free
}

extern "C" void kernel_launch(void* const* d_in, const int* in_sizes, int n_in,
                              void* d_out, int out_size, void* d_ws, size_t ws_size,
                              hipStream_t stream) {
    const float* inp    = (const float*)d_in[0];   // (N,L)
    const float* theta  = (const float*)d_in[1];   // (L,M)
    const float* coef   = (const float*)d_in[2];   // (M,)
    const float* rand_u = (const float*)d_in[3];   // (L,N)
    float* out = (float*)d_out;                    // N*L bits then N probs
    mps_sample_kernel<<<N_, THREADS, 0, stream>>>(inp, theta, coef, rand_u, out);
}

// Round 5
// 85.449 us; speedup vs baseline: 2.1029x; 1.6666x over previous
//
#include <hip/hip_runtime.h>
#include <math.h>

#define M_ 48
#define L_ 48
#define N_ 256
#define THREADS 512
#define NWAVE 8
#define PPT 3                  // pairs per thread: one row-chunk of 3 consecutive k

// R14: OCCUPANCY ROUND — 512 threads (8 waves = 2/SIMD), PPT 5->3.
// R13 counters (REP=4 visibility probe): kernel = 24 us/rep, VALUBusy 47.5%,
// Occupancy ~11% (1 wave/SIMD), VGPR 204 no-spill, bank-conflict ~6% of rep.
// Diagnosis: latency-bound at zero TLP — ~52% of cycles are exposed stalls.
// Fix: 2 waves/SIMD interleave stall bubbles in all parallel phases; per-SIMD
// issue work ~constant (2x153 vs 1x320 pair-slots). Serial round chain
// (wave_sum63+barrier+decision) unchanged. Predict kernel ~16 us, dur ~76.
// Post-mortems: R11 f32-LDS-table NEUTRAL (LDS BW overlapped); R12/R13
// measured K=24 us. Dead ends: R8 2x3 tiles, R9 spread prefetch, R10 stash
// capture (spill -> FETCH x8).
struct ChunkTab { short cm[THREADS]; short ck0[THREADS]; };
constexpr ChunkTab make_tab() {
    ChunkTab t{};
    int bsz[16] = {};
    for (int m = 0; m < 48; ++m)
        for (int j = 0; PPT * j < 48 - m; ++j) bsz[(m + PPT * j) & 15]++;
    int slot = 0;
    for (int r = 0; r < 64; ++r)
        for (int b = 0; b < 16; ++b)
            if (bsz[b] > r) {
                int cnt = 0;
                for (int m = 0; m < 48; ++m)
                    for (int j = 0; PPT * j < 48 - m; ++j)
                        if (((m + PPT * j) & 15) == b) {
                            if (cnt == r) { t.cm[slot] = (short)m; t.ck0[slot] = (short)(m + PPT * j); }
                            ++cnt;
                        }
                ++slot;
            }
    for (; slot < THREADS; ++slot) { t.cm[slot] = 0; t.ck0[slot] = 127; }  // dummy: weights 0
    return t;
}
__device__ constexpr ChunkTab g_tab = make_tab();

// f64 DPP wave-sum; lane 63 ends with the 64-lane total (VALU-latency stages,
// not ds_bpermute: R7's key win).
template<int CTRL, int RMASK>
__device__ __forceinline__ double dpp_add(double v) {
    int lo = __builtin_amdgcn_update_dpp(0, __double2loint(v), CTRL, RMASK, 0xf, true);
    int hi = __builtin_amdgcn_update_dpp(0, __double2hiint(v), CTRL, RMASK, 0xf, true);
    return v + __hiloint2double(hi, lo);
}
__device__ __forceinline__ double wave_sum63(double v) {
    v = dpp_add<0x111, 0xf>(v);   // row_shr:1
    v = dpp_add<0x112, 0xf>(v);   // row_shr:2
    v = dpp_add<0x114, 0xf>(v);   // row_shr:4
    v = dpp_add<0x118, 0xf>(v);   // row_shr:8
    v = dpp_add<0x142, 0xa>(v);   // row_bcast15
    v = dpp_add<0x143, 0xc>(v);   // row_bcast31 -> lane63 = total
    return v;
}

__launch_bounds__(THREADS, 2)
__global__ void mps_sample_kernel(const float* __restrict__ inp,
                                  const float* __restrict__ theta,
                                  const float* __restrict__ coef,
                                  const float* __restrict__ rand_u,
                                  float* __restrict__ out)
{
    const int n   = blockIdx.x;
    const int tid = threadIdx.x;

    __shared__ float  s_pxy[L_][M_][2];        // (px,py) f32 interleaved, b64-readable
    __shared__ double s_part[2][4][NWAVE];     // [parity][value][wave]
    __shared__ float  s_u[L_];

    const double PI_2 = 1.5707963267948966;

    // ---- trig init: pxy[l][m] = coef[m] * (cos, sin)(theta + inp*(m+1)*pi/2) ----
    #pragma unroll
    for (int i = 0; i < 5; ++i) {
        int j = tid + THREADS * i;
        if (j < L_ * M_) {
            int l = j / M_, m = j - l * M_;
            double a  = (double)inp[n * L_ + l] * ((double)(m + 1) * PI_2);
            double th = (double)theta[l * M_ + m];
            double sv, cv; sincos(th + a, &sv, &cv);
            double cf = (double)coef[m];
            s_pxy[l][m][0] = (float)(cf * cv);
            s_pxy[l][m][1] = (float)(cf * sv);
        }
    }
    if (tid < L_) s_u[tid] = rand_u[tid * N_ + n];

    // ---- row-chunk pair assignment: 3 pairs (cm, k0..k0+2) per thread ----
    const int cm = g_tab.cm[tid];
    const int k0 = g_tab.ck0[tid];
    int pk[PPT]; double wgt[PPT];
    #pragma unroll
    for (int i = 0; i < PPT; ++i) {
        int k = k0 + i;
        wgt[i] = (k > 47) ? 0.0 : ((k == cm) ? 1.0 : 2.0);
        pk[i]  = (k > 47) ? 47 : k;
    }
    __syncthreads();

    // ---- register checkpoints: ckpt[s] = w * prod_{l'>=8(s+1)} T_l' ----
    double ckpt[5][PPT];
    {
        double C[PPT];
        #pragma unroll
        for (int i = 0; i < PPT; ++i) C[i] = wgt[i];
        #pragma unroll
        for (int s = 4; s >= 0; --s) {
            #pragma unroll
            for (int lp = 7; lp >= 0; --lp) {
                int l = 8 * (s + 1) + lp;              // 47 .. 8
                float2 vm = *(const float2*)&s_pxy[l][cm][0];   // shared per thread
                #pragma unroll
                for (int i = 0; i < PPT; ++i) {
                    float2 vk = *(const float2*)&s_pxy[l][pk[i]][0];
                    C[i] *= (double)fmaf(vm.x, vk.x, vm.y * vk.y);
                }
            }
            #pragma unroll
            for (int i = 0; i < PPT; ++i) ckpt[s][i] = C[i];
        }
    }

    double G[PPT];
    #pragma unroll
    for (int i = 0; i < PPT; ++i) G[i] = 1.0;

    double denom = 0.0, initd = 1.0;
    float  myBit = 0.0f;

    #pragma unroll
    for (int seg = 0; seg < 6; ++seg) {
        // ---- segment stash: X[j][i], Y[j][i] (1 vm + 3 vk b64 loads per site) ----
        double X[8][PPT], Y[8][PPT];
        #pragma unroll
        for (int j = 0; j < 8; ++j) {
            int l2 = 8 * seg + j;
            float2 vm = *(const float2*)&s_pxy[l2][cm][0];
            #pragma unroll
            for (int i = 0; i < PPT; ++i) {
                float2 vk = *(const float2*)&s_pxy[l2][pk[i]][0];
                X[j][i] = (double)(vm.x * vk.x);
                Y[j][i] = (double)(vm.y * vk.y);
            }
        }
        // ---- register expansion from stash: R[j] = w * S_{8seg+j+1} ----
        double R[8][PPT];
        #pragma unroll
        for (int i = 0; i < PPT; ++i)
            R[7][i] = (seg == 5) ? wgt[i] : ckpt[seg == 5 ? 0 : seg][i];
        #pragma unroll
        for (int j = 6; j >= 0; --j)
            #pragma unroll
            for (int i = 0; i < PPT; ++i)
                R[j][i] = R[j + 1][i] * (X[j + 1][i] + Y[j + 1][i]);

        // ---- 4 iterations x 2 speculative steps, DPP-reduced ----
        #pragma unroll
        for (int half = 0; half < 4; ++half) {
            const int ls  = 2 * half;
            const int l   = 8 * seg + ls;
            const int par = half & 1;
            double n1L = 0.0, h0 = 0.0, h1 = 0.0, nT = 0.0;
            #pragma unroll
            for (int i = 0; i < PPT; ++i) {
                double t0 = G[i] * R[ls][i];
                double t1 = G[i] * R[ls + 1][i];
                n1L = fma(t0, Y[ls][i], n1L);
                if (seg == 0 && half == 0) nT = fma(t0, X[0][i], nT); // denom seed
                h0 = fma(t1 * X[ls][i], Y[ls + 1][i], h0);   // hypothesis bit_l = 0
                h1 = fma(t1 * Y[ls][i], Y[ls + 1][i], h1);   // hypothesis bit_l = 1
            }
            n1L = wave_sum63(n1L);
            h0  = wave_sum63(h0);
            h1  = wave_sum63(h1);
            if (seg == 0 && half == 0) nT = wave_sum63(nT);
            if ((tid & 63) == 63) {                 // lane 63 holds wave totals
                const int wv = tid >> 6;
                s_part[par][0][wv] = n1L; s_part[par][1][wv] = h0;
                s_part[par][2][wv] = h1;
                if (seg == 0 && half == 0) s_part[par][3][wv] = nT;
            }
            __syncthreads();
            double2 a0 = *(const double2*)&s_part[par][0][0];
            double2 b0 = *(const double2*)&s_part[par][0][2];
            double2 c0 = *(const double2*)&s_part[par][0][4];
            double2 d0 = *(const double2*)&s_part[par][0][6];
            double2 a1 = *(const double2*)&s_part[par][1][0];
            double2 b1 = *(const double2*)&s_part[par][1][2];
            double2 c1 = *(const double2*)&s_part[par][1][4];
            double2 d1 = *(const double2*)&s_part[par][1][6];
            double2 a2 = *(const double2*)&s_part[par][2][0];
            double2 b2 = *(const double2*)&s_part[par][2][2];
            double2 c2 = *(const double2*)&s_part[par][2][4];
            double2 d2 = *(const double2*)&s_part[par][2][6];
            double sn1 = ((a0.x + a0.y) + (b0.x + b0.y)) + ((c0.x + c0.y) + (d0.x + d0.y));
            double sh0 = ((a1.x + a1.y) + (b1.x + b1.y)) + ((c1.x + c1.y) + (d1.x + d1.y));
            double sh1 = ((a2.x + a2.y) + (b2.x + b2.y)) + ((c2.x + c2.y) + (d2.x + d2.y));
            if (seg == 0 && half == 0) {
                double2 a3 = *(const double2*)&s_part[par][3][0];
                double2 b3 = *(const double2*)&s_part[par][3][2];
                double2 c3 = *(const double2*)&s_part[par][3][4];
                double2 d3 = *(const double2*)&s_part[par][3][6];
                double snT = ((a3.x + a3.y) + (b3.x + b3.y)) + ((c3.x + c3.y) + (d3.x + d3.y));
                denom = fabs(snT + sn1);
                initd = denom;
            }
            // two bit decisions, division-free (denom = <psi|psi> > 0)
            double v1 = fabs(sn1);
            int bitA   = ((double)s_u[l] * denom < v1) ? 1 : 0;
            denom      = bitA ? v1 : fabs(denom - sn1);
            double n1b = bitA ? sh1 : sh0;
            double v2  = fabs(n1b);
            int bitB   = ((double)s_u[l + 1] * denom < v2) ? 1 : 0;
            denom      = bitB ? v2 : fabs(denom - n1b);
            // fused two-step prefix update from stash
            #pragma unroll
            for (int i = 0; i < PPT; ++i) {
                double c0 = bitA ? Y[ls][i]     : X[ls][i];
                double c1 = bitB ? Y[ls + 1][i] : X[ls + 1][i];
                G[i] *= c0 * c1;
            }
            if (tid == l)     myBit = (float)bitA;
            if (tid == l + 1) myBit = (float)bitB;
        }
    }

    if (tid < L_)  out[n * L_ + tid] = myBit;                 // bits, one burst
    if (tid == 0)  out[N_ * L_ + n] = (float)(denom / initd); // P_m carried free
}

extern "C" void kernel_launch(void* const* d_in, const int* in_sizes, int n_in,
                              void* d_out, int out_size, void* d_ws, size_t ws_size,
                              hipStream_t stream) {
    const float* inp    = (const float*)d_in[0];   // (N,L)
    const float* theta  = (const float*)d_in[1];   // (L,M)
    const float* coef   = (const float*)d_in[2];   // (M,)
    const float* rand_u = (const float*)d_in[3];   // (L,N)
    float* out = (float*)d_out;                    // N*L bits then N probs
    mps_sample_kernel<<<N_, THREADS, 0, stream>>>(inp, theta, coef, rand_u, out);
}

// Round 6
// 84.778 us; speedup vs baseline: 2.1196x; 1.0079x over previous
//
#include <hip/hip_runtime.h>
#include <math.h>

#define M_ 48
#define L_ 48
#define N_ 256
#define THREADS 512
#define NWAVE 8
#define PPT 3                  // pairs per thread: one row-chunk of 3 consecutive k

// R15: DE-SPILL ROUND — 512 threads (2 waves/SIMD) with lazy X/Y reload.
// R14 post-mortem: profiled kernel dur (82us) contradicted bench slope
// (dur_us 85.4 => unprofiled kernel ~24-26us) -> profiling artifact at 512
// threads; trust bench dur + R12 slope instrument. Trustworthy R14 signal:
// VGPR_Count=112 << ~250 natural live-set => forced scratch spill (512-thr
// blocks must fit 256 VGPR for 2 waves/SIMD). This round keeps only
// T[8][3]=X+Y for the suffix chain and re-loads X/Y per round-pair from LDS
// (8 ds_read_b64 in the post-barrier region, overlapped with the decision
// chain; s_pxy is read-only). Peak live-set ~170-190 VGPR -> no spill.
// FP ops per pair bit-identical to R14 (passed, absmax 0).
// Discriminator: H1 spill-ate-the-gain -> dur ~74-78; H2 serial-bound ->
// dur ~83-86 and occupancy direction closes.
// Post-mortems: R11 f32-LDS-table NEUTRAL; R12/R13 K=24us, VALUBusy 47.5%,
// 1 wave/SIMD. Dead ends: R8 2x3 tiles, R9 spread prefetch, R10 stash
// capture (spill -> FETCH x8), R14 full-stash @512thr (spill, VGPR 112).
struct ChunkTab { short cm[THREADS]; short ck0[THREADS]; };
constexpr ChunkTab make_tab() {
    ChunkTab t{};
    int bsz[16] = {};
    for (int m = 0; m < 48; ++m)
        for (int j = 0; PPT * j < 48 - m; ++j) bsz[(m + PPT * j) & 15]++;
    int slot = 0;
    for (int r = 0; r < 64; ++r)
        for (int b = 0; b < 16; ++b)
            if (bsz[b] > r) {
                int cnt = 0;
                for (int m = 0; m < 48; ++m)
                    for (int j = 0; PPT * j < 48 - m; ++j)
                        if (((m + PPT * j) & 15) == b) {
                            if (cnt == r) { t.cm[slot] = (short)m; t.ck0[slot] = (short)(m + PPT * j); }
                            ++cnt;
                        }
                ++slot;
            }
    for (; slot < THREADS; ++slot) { t.cm[slot] = 0; t.ck0[slot] = 127; }  // dummy: weights 0
    return t;
}
__device__ constexpr ChunkTab g_tab = make_tab();

// f64 DPP wave-sum; lane 63 ends with the 64-lane total (VALU-latency stages,
// not ds_bpermute: R7's key win).
template<int CTRL, int RMASK>
__device__ __forceinline__ double dpp_add(double v) {
    int lo = __builtin_amdgcn_update_dpp(0, __double2loint(v), CTRL, RMASK, 0xf, true);
    int hi = __builtin_amdgcn_update_dpp(0, __double2hiint(v), CTRL, RMASK, 0xf, true);
    return v + __hiloint2double(hi, lo);
}
__device__ __forceinline__ double wave_sum63(double v) {
    v = dpp_add<0x111, 0xf>(v);   // row_shr:1
    v = dpp_add<0x112, 0xf>(v);   // row_shr:2
    v = dpp_add<0x114, 0xf>(v);   // row_shr:4
    v = dpp_add<0x118, 0xf>(v);   // row_shr:8
    v = dpp_add<0x142, 0xa>(v);   // row_bcast15
    v = dpp_add<0x143, 0xc>(v);   // row_bcast31 -> lane63 = total
    return v;
}

__launch_bounds__(THREADS, 2)
__global__ void mps_sample_kernel(const float* __restrict__ inp,
                                  const float* __restrict__ theta,
                                  const float* __restrict__ coef,
                                  const float* __restrict__ rand_u,
                                  float* __restrict__ out)
{
    const int n   = blockIdx.x;
    const int tid = threadIdx.x;

    __shared__ float  s_pxy[L_][M_][2];        // (px,py) f32 interleaved, b64-readable
    __shared__ double s_part[2][4][NWAVE];     // [parity][value][wave]
    __shared__ float  s_u[L_];

    const double PI_2 = 1.5707963267948966;

    // ---- trig init: pxy[l][m] = coef[m] * (cos, sin)(theta + inp*(m+1)*pi/2) ----
    #pragma unroll
    for (int i = 0; i < 5; ++i) {
        int j = tid + THREADS * i;
        if (j < L_ * M_) {
            int l = j / M_, m = j - l * M_;
            double a  = (double)inp[n * L_ + l] * ((double)(m + 1) * PI_2);
            double th = (double)theta[l * M_ + m];
            double sv, cv; sincos(th + a, &sv, &cv);
            double cf = (double)coef[m];
            s_pxy[l][m][0] = (float)(cf * cv);
            s_pxy[l][m][1] = (float)(cf * sv);
        }
    }
    if (tid < L_) s_u[tid] = rand_u[tid * N_ + n];

    // ---- row-chunk pair assignment: 3 pairs (cm, k0..k0+2) per thread ----
    const int cm = g_tab.cm[tid];
    const int k0 = g_tab.ck0[tid];
    int pk[PPT]; double wgt[PPT];
    #pragma unroll
    for (int i = 0; i < PPT; ++i) {
        int k = k0 + i;
        wgt[i] = (k > 47) ? 0.0 : ((k == cm) ? 1.0 : 2.0);
        pk[i]  = (k > 47) ? 47 : k;
    }
    __syncthreads();

    // ---- register checkpoints: ckpt[s] = w * prod_{l'>=8(s+1)} T_l' ----
    double ckpt[5][PPT];
    {
        double C[PPT];
        #pragma unroll
        for (int i = 0; i < PPT; ++i) C[i] = wgt[i];
        #pragma unroll
        for (int s = 4; s >= 0; --s) {
            #pragma unroll
            for (int lp = 7; lp >= 0; --lp) {
                int l = 8 * (s + 1) + lp;              // 47 .. 8
                float2 vm = *(const float2*)&s_pxy[l][cm][0];   // shared per thread
                #pragma unroll
                for (int i = 0; i < PPT; ++i) {
                    float2 vk = *(const float2*)&s_pxy[l][pk[i]][0];
                    C[i] *= (double)fmaf(vm.x, vk.x, vm.y * vk.y);
                }
            }
            #pragma unroll
            for (int i = 0; i < PPT; ++i) ckpt[s][i] = C[i];
        }
    }

    double G[PPT];
    #pragma unroll
    for (int i = 0; i < PPT; ++i) G[i] = 1.0;

    double denom = 0.0, initd = 1.0;
    float  myBit = 0.0f;

    #pragma unroll
    for (int seg = 0; seg < 6; ++seg) {
        // ---- segment T-stash: T[j][i] = X+Y only (1 vm + 3 vk b64 loads/site) ----
        double T[8][PPT];
        #pragma unroll
        for (int j = 0; j < 8; ++j) {
            int l2 = 8 * seg + j;
            float2 vm = *(const float2*)&s_pxy[l2][cm][0];
            #pragma unroll
            for (int i = 0; i < PPT; ++i) {
                float2 vk = *(const float2*)&s_pxy[l2][pk[i]][0];
                T[j][i] = (double)(vm.x * vk.x) + (double)(vm.y * vk.y);
            }
        }
        // ---- register expansion: R[j] = w * S_{8seg+j+1}; T dies after this ----
        double R[8][PPT];
        #pragma unroll
        for (int i = 0; i < PPT; ++i)
            R[7][i] = (seg == 5) ? wgt[i] : ckpt[seg == 5 ? 0 : seg][i];
        #pragma unroll
        for (int j = 6; j >= 0; --j)
            #pragma unroll
            for (int i = 0; i < PPT; ++i)
                R[j][i] = R[j + 1][i] * T[j + 1][i];

        // ---- 4 iterations x 2 speculative steps, DPP-reduced ----
        #pragma unroll
        for (int half = 0; half < 4; ++half) {
            const int ls  = 2 * half;
            const int l   = 8 * seg + ls;
            const int par = half & 1;
            // lazy X/Y reload for the two sites of this round-pair; these LDS
            // loads sit in the post-barrier region and overlap the previous
            // round's decision chain (s_pxy is read-only after init).
            float2 vm0 = *(const float2*)&s_pxy[l][cm][0];
            float2 vm1 = *(const float2*)&s_pxy[l + 1][cm][0];
            double X0[PPT], Y0[PPT], X1[PPT], Y1[PPT];
            #pragma unroll
            for (int i = 0; i < PPT; ++i) {
                float2 vk0 = *(const float2*)&s_pxy[l][pk[i]][0];
                float2 vk1 = *(const float2*)&s_pxy[l + 1][pk[i]][0];
                X0[i] = (double)(vm0.x * vk0.x);
                Y0[i] = (double)(vm0.y * vk0.y);
                X1[i] = (double)(vm1.x * vk1.x);
                Y1[i] = (double)(vm1.y * vk1.y);
            }
            double n1L = 0.0, h0 = 0.0, h1 = 0.0, nT = 0.0;
            #pragma unroll
            for (int i = 0; i < PPT; ++i) {
                double t0 = G[i] * R[ls][i];
                double t1 = G[i] * R[ls + 1][i];
                n1L = fma(t0, Y0[i], n1L);
                if (seg == 0 && half == 0) nT = fma(t0, X0[i], nT); // denom seed
                h0 = fma(t1 * X0[i], Y1[i], h0);   // hypothesis bit_l = 0
                h1 = fma(t1 * Y0[i], Y1[i], h1);   // hypothesis bit_l = 1
            }
            n1L = wave_sum63(n1L);
            h0  = wave_sum63(h0);
            h1  = wave_sum63(h1);
            if (seg == 0 && half == 0) nT = wave_sum63(nT);
            if ((tid & 63) == 63) {                 // lane 63 holds wave totals
                const int wv = tid >> 6;
                s_part[par][0][wv] = n1L; s_part[par][1][wv] = h0;
                s_part[par][2][wv] = h1;
                if (seg == 0 && half == 0) s_part[par][3][wv] = nT;
            }
            __syncthreads();
            double2 a0 = *(const double2*)&s_part[par][0][0];
            double2 b0 = *(const double2*)&s_part[par][0][2];
            double2 c0v = *(const double2*)&s_part[par][0][4];
            double2 d0v = *(const double2*)&s_part[par][0][6];
            double2 a1 = *(const double2*)&s_part[par][1][0];
            double2 b1 = *(const double2*)&s_part[par][1][2];
            double2 c1v = *(const double2*)&s_part[par][1][4];
            double2 d1v = *(const double2*)&s_part[par][1][6];
            double2 a2 = *(const double2*)&s_part[par][2][0];
            double2 b2 = *(const double2*)&s_part[par][2][2];
            double2 c2v = *(const double2*)&s_part[par][2][4];
            double2 d2v = *(const double2*)&s_part[par][2][6];
            double sn1 = ((a0.x + a0.y) + (b0.x + b0.y)) + ((c0v.x + c0v.y) + (d0v.x + d0v.y));
            double sh0 = ((a1.x + a1.y) + (b1.x + b1.y)) + ((c1v.x + c1v.y) + (d1v.x + d1v.y));
            double sh1 = ((a2.x + a2.y) + (b2.x + b2.y)) + ((c2v.x + c2v.y) + (d2v.x + d2v.y));
            if (seg == 0 && half == 0) {
                double2 a3 = *(const double2*)&s_part[par][3][0];
                double2 b3 = *(const double2*)&s_part[par][3][2];
                double2 c3v = *(const double2*)&s_part[par][3][4];
                double2 d3v = *(const double2*)&s_part[par][3][6];
                double snT = ((a3.x + a3.y) + (b3.x + b3.y)) + ((c3v.x + c3v.y) + (d3v.x + d3v.y));
                denom = fabs(snT + sn1);
                initd = denom;
            }
            // two bit decisions, division-free (denom = <psi|psi> > 0)
            double v1 = fabs(sn1);
            int bitA   = ((double)s_u[l] * denom < v1) ? 1 : 0;
            denom      = bitA ? v1 : fabs(denom - sn1);
            double n1b = bitA ? sh1 : sh0;
            double v2  = fabs(n1b);
            int bitB   = ((double)s_u[l + 1] * denom < v2) ? 1 : 0;
            denom      = bitB ? v2 : fabs(denom - n1b);
            // fused two-step prefix update from the reloaded values
            #pragma unroll
            for (int i = 0; i < PPT; ++i) {
                double c0 = bitA ? Y0[i] : X0[i];
                double c1 = bitB ? Y1[i] : X1[i];
                G[i] *= c0 * c1;
            }
            if (tid == l)     myBit = (float)bitA;
            if (tid == l + 1) myBit = (float)bitB;
        }
    }

    if (tid < L_)  out[n * L_ + tid] = myBit;                 // bits, one burst
    if (tid == 0)  out[N_ * L_ + n] = (float)(denom / initd); // P_m carried free
}

extern "C" void kernel_launch(void* const* d_in, const int* in_sizes, int n_in,
                              void* d_out, int out_size, void* d_ws, size_t ws_size,
                              hipStream_t stream) {
    const float* inp    = (const float*)d_in[0];   // (N,L)
    const float* theta  = (const float*)d_in[1];   // (L,M)
    const float* coef   = (const float*)d_in[2];   // (M,)
    const float* rand_u = (const float*)d_in[3];   // (L,N)
    float* out = (float*)d_out;                    // N*L bits then N probs
    mps_sample_kernel<<<N_, THREADS, 0, stream>>>(inp, theta, coef, rand_u, out);
}